// Round 1
// baseline (152.932 us; speedup 1.0000x reference)
//
#include <hip/hip_runtime.h>

// Problem constants (match reference)
#define NS 6
#define NC 64
#define HF 44
#define WF 80
#define HW (HF * WF)       // 3520
#define NZ 16
#define NY 100
#define NX 100
#define XYZ (NX * NY * NZ) // 160000

// ---------------------------------------------------------------------------
// Kernel 1: compose per-camera projection matrices (rows 0..2 of pix_T_cam0)
// and the z_cam row (row 2 of camXs_T_cam0). 16 floats per camera into ws.
// ---------------------------------------------------------------------------
__global__ void setup_mats(const float* __restrict__ pix,
                           const float* __restrict__ c0TX,
                           float* __restrict__ mats) {
    int s = threadIdx.x;
    if (s >= NS) return;
    const float* T = c0TX + s * 16;   // cam0_T_camXs[s], row-major 4x4
    // inv = [R^T | -R^T t ; 0 0 0 1]
    float inv[4][4];
    for (int i = 0; i < 3; ++i) {
        for (int j = 0; j < 3; ++j) inv[i][j] = T[j * 4 + i];
        inv[i][3] = -(T[0 * 4 + i] * T[0 * 4 + 3] +
                      T[1 * 4 + i] * T[1 * 4 + 3] +
                      T[2 * 4 + i] * T[2 * 4 + 3]);
    }
    inv[3][0] = 0.f; inv[3][1] = 0.f; inv[3][2] = 0.f; inv[3][3] = 1.f;

    const float sx = (float)WF / 640.0f;  // WF / W_IMG
    const float sy = (float)HF / 352.0f;  // HF / H_IMG
    const float* K = pix + s * 16;
    float fp[3][4];
    for (int j = 0; j < 4; ++j) {
        fp[0][j] = sx * K[0 * 4 + j];
        fp[1][j] = sy * K[1 * 4 + j];
        fp[2][j] = K[2 * 4 + j];
    }
    float* M = mats + s * 16;
    for (int i = 0; i < 3; ++i)
        for (int j = 0; j < 4; ++j) {
            float acc = 0.f;
            for (int k = 0; k < 4; ++k) acc += fp[i][k] * inv[k][j];
            M[i * 4 + j] = acc;
        }
    // z_cam row = inv row 2
    for (int j = 0; j < 4; ++j) M[12 + j] = inv[2][j];
}

// ---------------------------------------------------------------------------
// Kernel 2: transpose features (S,C,HF,WF) -> (S,HF*WF,C) so that the 64
// channels at one pixel are contiguous (256 B) for coalesced gather.
// Tiled 64x64 via LDS. HW = 3520 = 55 * 64 exactly.
// ---------------------------------------------------------------------------
__global__ __launch_bounds__(256) void transpose_feat(
        const float* __restrict__ in, float* __restrict__ outT) {
    __shared__ float tile[64 * 65];
    int b = blockIdx.x;
    int s = b / 55;
    int hw0 = (b % 55) * 64;
    int t = threadIdx.x;
#pragma unroll
    for (int i = 0; i < 16; ++i) {
        int e = t + i * 256;
        int c = e >> 6, w = e & 63;
        tile[c * 65 + w] = in[((size_t)(s * NC + c)) * HW + hw0 + w];
    }
    __syncthreads();
#pragma unroll
    for (int i = 0; i < 16; ++i) {
        int e = t + i * 256;
        int hwl = e >> 6, c = e & 63;
        outT[((size_t)s * HW + hw0 + hwl) * NC + c] = tile[c * 65 + hwl];
    }
}

// ---------------------------------------------------------------------------
// Kernel 3: main pooling. One block per (x,y) column: 16 z-slices x 64 ch.
// 4 waves, each wave does 4 z values; lane = channel. Projection math is
// wave-uniform; camera-valid branch is wave-uniform (no divergence).
// Results staged in LDS (stride 17, conflict-free), written as float4.
// ---------------------------------------------------------------------------
template <bool TRANS>
__global__ __launch_bounds__(256) void volpool(
        const float* __restrict__ feat,
        const float* __restrict__ mats,
        float* __restrict__ out) {
    __shared__ float lds[NC * 17];
    __shared__ float m[NS * 16];
    int t = threadIdx.x;
    if (t < NS * 16) m[t] = mats[t];
    __syncthreads();

    int b = blockIdx.x;
    int x = b % NX, y = b / NX;
    float xw = -40.0f + 0.8f * ((float)x + 0.5f);
    float yw = -40.0f + 0.8f * ((float)y + 0.5f);
    int wave = t >> 6, lane = t & 63;

#pragma unroll
    for (int zi = 0; zi < 4; ++zi) {
        int z = wave * 4 + zi;
        float zw = -1.0f + 0.4f * ((float)z + 0.5f);
        float sum = 0.f, cnt = 0.f;
        for (int s = 0; s < NS; ++s) {
            const float* M = m + s * 16;
            float px = M[0] * xw + M[1] * yw + M[2]  * zw + M[3];
            float py = M[4] * xw + M[5] * yw + M[6]  * zw + M[7];
            float pz = M[8] * xw + M[9] * yw + M[10] * zw + M[11];
            float zc = M[12] * xw + M[13] * yw + M[14] * zw + M[15];
            float denom = fmaxf(pz, 1e-6f);
            float xp = px / denom, yp = py / denom;
            bool valid = (xp > -0.5f) & (xp < (float)WF - 0.5f) &
                         (yp > -0.5f) & (yp < (float)HF - 0.5f) & (zc > 0.0f);
            if (!valid) continue;   // wave-uniform branch
            float xs = xp - 0.5f, ys = yp - 0.5f;
            float x0f = floorf(xs), y0f = floorf(ys);
            float wx1 = xs - x0f, wy1 = ys - y0f;
            float wx0 = 1.f - wx1, wy0 = 1.f - wy1;
            int x0 = (int)x0f, y0 = (int)y0f;
            int x1 = x0 + 1, y1 = y0 + 1;
            bool bx0 = (x0 >= 0) & (x0 < WF);
            bool bx1 = (x1 >= 0) & (x1 < WF);
            bool by0 = (y0 >= 0) & (y0 < HF);
            bool by1 = (y1 >= 0) & (y1 < HF);
            int x0c = min(max(x0, 0), WF - 1);
            int x1c = min(max(x1, 0), WF - 1);
            int y0c = min(max(y0, 0), HF - 1);
            int y1c = min(max(y1, 0), HF - 1);
            float f00 = 0.f, f10 = 0.f, f01 = 0.f, f11 = 0.f;
            if (TRANS) {
                const float* base = feat + (size_t)s * HW * NC;
                if (bx0 & by0) f00 = base[((size_t)y0c * WF + x0c) * NC + lane];
                if (bx1 & by0) f10 = base[((size_t)y0c * WF + x1c) * NC + lane];
                if (bx0 & by1) f01 = base[((size_t)y1c * WF + x0c) * NC + lane];
                if (bx1 & by1) f11 = base[((size_t)y1c * WF + x1c) * NC + lane];
            } else {
                const float* base = feat + ((size_t)(s * NC + lane)) * HW;
                if (bx0 & by0) f00 = base[y0c * WF + x0c];
                if (bx1 & by0) f10 = base[y0c * WF + x1c];
                if (bx0 & by1) f01 = base[y1c * WF + x0c];
                if (bx1 & by1) f11 = base[y1c * WF + x1c];
            }
            float v = wx0 * wy0 * f00 + wx1 * wy0 * f10 +
                      wx0 * wy1 * f01 + wx1 * wy1 * f11;
            sum += v;
            cnt += (v != 0.0f) ? 1.0f : 0.0f;
        }
        lds[lane * 17 + z] = sum / (cnt + 1e-6f);
    }
    __syncthreads();

    // write out: out[((c*NX + x)*NY + y)*NZ + z]; float4 over z
    int c = t >> 2, zq = t & 3;
    float4 v4;
    v4.x = lds[c * 17 + zq * 4 + 0];
    v4.y = lds[c * 17 + zq * 4 + 1];
    v4.z = lds[c * 17 + zq * 4 + 2];
    v4.w = lds[c * 17 + zq * 4 + 3];
    float* o = out + (size_t)c * XYZ + ((size_t)x * NY + y) * NZ + zq * 4;
    *(float4*)o = v4;
}

// ---------------------------------------------------------------------------
extern "C" void kernel_launch(void* const* d_in, const int* in_sizes, int n_in,
                              void* d_out, int out_size, void* d_ws, size_t ws_size,
                              hipStream_t stream) {
    const float* features = (const float*)d_in[0];
    const float* pix      = (const float*)d_in[1];
    const float* c0TX     = (const float*)d_in[2];
    float* out  = (float*)d_out;
    float* mats = (float*)d_ws;                        // 96 floats
    float* featT = (float*)((char*)d_ws + 1024);       // transposed features
    size_t need = 1024 + sizeof(float) * (size_t)NS * HW * NC;

    hipLaunchKernelGGL(setup_mats, dim3(1), dim3(64), 0, stream, pix, c0TX, mats);
    if (ws_size >= need) {
        hipLaunchKernelGGL(transpose_feat, dim3(NS * 55), dim3(256), 0, stream,
                           features, featT);
        hipLaunchKernelGGL((volpool<true>), dim3(NX * NY), dim3(256), 0, stream,
                           featT, mats, out);
    } else {
        hipLaunchKernelGGL((volpool<false>), dim3(NX * NY), dim3(256), 0, stream,
                           features, mats, out);
    }
}

// Round 2
// 87.593 us; speedup vs baseline: 1.7459x; 1.7459x over previous
//
#include <hip/hip_runtime.h>

// Problem constants (match reference)
#define NS 6
#define NC 64
#define HF 44
#define WF 80
#define HW (HF * WF)       // 3520
#define NZ 16
#define NY 100
#define NX 100
#define XYZ (NX * NY * NZ) // 160000

// ---------------------------------------------------------------------------
// Kernel 1: transpose features (S,C,HF,WF) -> (S,HF*WF,C) so that the 64
// channels at one pixel are contiguous (256 B) for coalesced float4 gathers.
// Tiled 64x64 via LDS. HW = 3520 = 55 * 64 exactly.
// ---------------------------------------------------------------------------
__global__ __launch_bounds__(256) void transpose_feat(
        const float* __restrict__ in, float* __restrict__ outT) {
    __shared__ float tile[64 * 65];
    int b = blockIdx.x;
    int s = b / 55;
    int hw0 = (b % 55) * 64;
    int t = threadIdx.x;
#pragma unroll
    for (int i = 0; i < 16; ++i) {
        int e = t + i * 256;
        int c = e >> 6, w = e & 63;
        tile[c * 65 + w] = in[((size_t)(s * NC + c)) * HW + hw0 + w];
    }
    __syncthreads();
#pragma unroll
    for (int i = 0; i < 16; ++i) {
        int e = t + i * 256;
        int hwl = e >> 6, c = e & 63;
        outT[((size_t)s * HW + hw0 + hwl) * NC + c] = tile[c * 65 + hwl];
    }
}

// ---------------------------------------------------------------------------
// Kernel 2: main pooling. One block per (x,y) column: 16 z x 64 ch.
// Phase A: t<6 build camera matrices (fused, no setup kernel); t<96 compute
//          per-(z,cam) projection -> folded weights + corner offsets + flag
//          into LDS (computed ONCE instead of 64x per lane as in R0).
// Phase B: thread = (z = t>>4, chan-group = t&15); float4 gathers
//          (16 lanes -> 256 B coalesced), bilinear FMA, count/sum.
// Phase C: stage in LDS (stride 17, conflict-free) -> coalesced float4 out.
// ---------------------------------------------------------------------------
template <bool TRANS>
__global__ __launch_bounds__(256) void volpool(
        const float* __restrict__ feat,
        const float* __restrict__ pix,
        const float* __restrict__ c0TX,
        float* __restrict__ out) {
    __shared__ float  mlds[NS * 16];
    __shared__ float4 wts[96];
    __shared__ int4   offs[96];
    __shared__ int    vflags[96];
    __shared__ float  ostage[NC * 17];

    int t = threadIdx.x;
    int b = blockIdx.x;
    int x = b % NX, y = b / NX;

    // ---- Phase A1: camera matrices (rows 0..2 of pix_T_cam0, z_cam row) ----
    if (t < NS) {
        const float* T = c0TX + t * 16;   // cam0_T_camXs[t]
        float inv[4][4];
        for (int i = 0; i < 3; ++i) {
            for (int j = 0; j < 3; ++j) inv[i][j] = T[j * 4 + i];
            inv[i][3] = -(T[0 * 4 + i] * T[0 * 4 + 3] +
                          T[1 * 4 + i] * T[1 * 4 + 3] +
                          T[2 * 4 + i] * T[2 * 4 + 3]);
        }
        inv[3][0] = 0.f; inv[3][1] = 0.f; inv[3][2] = 0.f; inv[3][3] = 1.f;
        const float sx = (float)WF / 640.0f;
        const float sy = (float)HF / 352.0f;
        const float* K = pix + t * 16;
        float fp[3][4];
        for (int j = 0; j < 4; ++j) {
            fp[0][j] = sx * K[0 * 4 + j];
            fp[1][j] = sy * K[1 * 4 + j];
            fp[2][j] = K[2 * 4 + j];
        }
        float* M = mlds + t * 16;
        for (int i = 0; i < 3; ++i)
            for (int j = 0; j < 4; ++j) {
                float acc = 0.f;
                for (int k = 0; k < 4; ++k) acc += fp[i][k] * inv[k][j];
                M[i * 4 + j] = acc;
            }
        for (int j = 0; j < 4; ++j) M[12 + j] = inv[2][j];
    }
    __syncthreads();

    // ---- Phase A2: per-(z,cam) projection params ----
    if (t < 96) {
        int s = t % NS, z = t / NS;
        const float* M = mlds + s * 16;
        float xw = -40.0f + 0.8f * ((float)x + 0.5f);
        float yw = -40.0f + 0.8f * ((float)y + 0.5f);
        float zw = -1.0f + 0.4f * ((float)z + 0.5f);
        float px = M[0] * xw + M[1] * yw + M[2]  * zw + M[3];
        float py = M[4] * xw + M[5] * yw + M[6]  * zw + M[7];
        float pz = M[8] * xw + M[9] * yw + M[10] * zw + M[11];
        float zc = M[12] * xw + M[13] * yw + M[14] * zw + M[15];
        float denom = fmaxf(pz, 1e-6f);
        float xp = px / denom, yp = py / denom;
        bool valid = (xp > -0.5f) & (xp < (float)WF - 0.5f) &
                     (yp > -0.5f) & (yp < (float)HF - 0.5f) & (zc > 0.0f);
        vflags[t] = valid ? 1 : 0;
        if (valid) {
            float xs = xp - 0.5f, ys = yp - 0.5f;
            float x0f = floorf(xs), y0f = floorf(ys);
            float wx1 = xs - x0f, wy1 = ys - y0f;
            float wx0 = 1.f - wx1, wy0 = 1.f - wy1;
            int x0 = (int)x0f, y0 = (int)y0f;
            int x1 = x0 + 1, y1 = y0 + 1;
            bool bx0 = (x0 >= 0) & (x0 < WF);
            bool bx1 = (x1 >= 0) & (x1 < WF);
            bool by0 = (y0 >= 0) & (y0 < HF);
            bool by1 = (y1 >= 0) & (y1 < HF);
            int x0c = min(max(x0, 0), WF - 1);
            int x1c = min(max(x1, 0), WF - 1);
            int y0c = min(max(y0, 0), HF - 1);
            int y1c = min(max(y1, 0), HF - 1);
            float4 w;
            w.x = wx0 * wy0 * (float)(bx0 & by0);
            w.y = wx1 * wy0 * (float)(bx1 & by0);
            w.z = wx0 * wy1 * (float)(bx0 & by1);
            w.w = wx1 * wy1 * (float)(bx1 & by1);
            int p00 = y0c * WF + x0c, p10 = y0c * WF + x1c;
            int p01 = y1c * WF + x0c, p11 = y1c * WF + x1c;
            int4 o;
            if (TRANS) {
                o.x = (s * HW + p00) * NC;
                o.y = (s * HW + p10) * NC;
                o.z = (s * HW + p01) * NC;
                o.w = (s * HW + p11) * NC;
            } else {
                o.x = s * NC * HW + p00;
                o.y = s * NC * HW + p10;
                o.z = s * NC * HW + p01;
                o.w = s * NC * HW + p11;
            }
            wts[t] = w;
            offs[t] = o;
        }
    }
    __syncthreads();

    // ---- Phase B: gather + bilinear + accumulate ----
    int cg = t & 15, z = t >> 4;
    float4 sum = make_float4(0.f, 0.f, 0.f, 0.f);
    float4 cnt = make_float4(0.f, 0.f, 0.f, 0.f);
    for (int s = 0; s < NS; ++s) {
        int idx = z * NS + s;
        if (!vflags[idx]) continue;
        float4 w = wts[idx];
        int4 o = offs[idx];
        float4 f00, f10, f01, f11;
        if (TRANS) {
            int ch4 = cg << 2;
            f00 = *(const float4*)(feat + o.x + ch4);
            f10 = *(const float4*)(feat + o.y + ch4);
            f01 = *(const float4*)(feat + o.z + ch4);
            f11 = *(const float4*)(feat + o.w + ch4);
        } else {
            int c0 = cg << 2;
            f00.x = feat[o.x + (c0 + 0) * HW]; f00.y = feat[o.x + (c0 + 1) * HW];
            f00.z = feat[o.x + (c0 + 2) * HW]; f00.w = feat[o.x + (c0 + 3) * HW];
            f10.x = feat[o.y + (c0 + 0) * HW]; f10.y = feat[o.y + (c0 + 1) * HW];
            f10.z = feat[o.y + (c0 + 2) * HW]; f10.w = feat[o.y + (c0 + 3) * HW];
            f01.x = feat[o.z + (c0 + 0) * HW]; f01.y = feat[o.z + (c0 + 1) * HW];
            f01.z = feat[o.z + (c0 + 2) * HW]; f01.w = feat[o.z + (c0 + 3) * HW];
            f11.x = feat[o.w + (c0 + 0) * HW]; f11.y = feat[o.w + (c0 + 1) * HW];
            f11.z = feat[o.w + (c0 + 2) * HW]; f11.w = feat[o.w + (c0 + 3) * HW];
        }
        float vx = w.x * f00.x + w.y * f10.x + w.z * f01.x + w.w * f11.x;
        float vy = w.x * f00.y + w.y * f10.y + w.z * f01.y + w.w * f11.y;
        float vz = w.x * f00.z + w.y * f10.z + w.z * f01.z + w.w * f11.z;
        float vw = w.x * f00.w + w.y * f10.w + w.z * f01.w + w.w * f11.w;
        sum.x += vx; cnt.x += (vx != 0.0f) ? 1.0f : 0.0f;
        sum.y += vy; cnt.y += (vy != 0.0f) ? 1.0f : 0.0f;
        sum.z += vz; cnt.z += (vz != 0.0f) ? 1.0f : 0.0f;
        sum.w += vw; cnt.w += (vw != 0.0f) ? 1.0f : 0.0f;
    }
    int c0 = cg << 2;
    ostage[(c0 + 0) * 17 + z] = sum.x / (cnt.x + 1e-6f);
    ostage[(c0 + 1) * 17 + z] = sum.y / (cnt.y + 1e-6f);
    ostage[(c0 + 2) * 17 + z] = sum.z / (cnt.z + 1e-6f);
    ostage[(c0 + 3) * 17 + z] = sum.w / (cnt.w + 1e-6f);
    __syncthreads();

    // ---- Phase C: coalesced float4 write (out[((c*NX+x)*NY+y)*NZ+z]) ----
    int c = t >> 2, zq = t & 3;
    float4 v4;
    v4.x = ostage[c * 17 + zq * 4 + 0];
    v4.y = ostage[c * 17 + zq * 4 + 1];
    v4.z = ostage[c * 17 + zq * 4 + 2];
    v4.w = ostage[c * 17 + zq * 4 + 3];
    float* o = out + (size_t)c * XYZ + ((size_t)x * NY + y) * NZ + zq * 4;
    *(float4*)o = v4;
}

// ---------------------------------------------------------------------------
extern "C" void kernel_launch(void* const* d_in, const int* in_sizes, int n_in,
                              void* d_out, int out_size, void* d_ws, size_t ws_size,
                              hipStream_t stream) {
    const float* features = (const float*)d_in[0];
    const float* pix      = (const float*)d_in[1];
    const float* c0TX     = (const float*)d_in[2];
    float* out   = (float*)d_out;
    float* featT = (float*)d_ws;
    size_t need = sizeof(float) * (size_t)NS * HW * NC;

    if (ws_size >= need) {
        hipLaunchKernelGGL(transpose_feat, dim3(NS * 55), dim3(256), 0, stream,
                           features, featT);
        hipLaunchKernelGGL((volpool<true>), dim3(NX * NY), dim3(256), 0, stream,
                           featT, pix, c0TX, out);
    } else {
        hipLaunchKernelGGL((volpool<false>), dim3(NX * NY), dim3(256), 0, stream,
                           features, pix, c0TX, out);
    }
}